// Round 13
// baseline (30.575 us; speedup 1.0000x reference)
//
#include <hip/hip_runtime.h>
#include <math.h>

#define TPB 512
#define WAVES 8
#define RAYS_PB 256      // rays per block
#define RPT 4            // rays per thread (RAYS_PB / 64)
#define MAXPTS 2048      // points staged in LDS per chunk (32 KB as float4)

// ---------------------------------------------------------------------------
// Single compute dispatch: grid = (ceil(M/256), B), block = 512 (8 waves).
// Identical to the best-measured R6 main (fused staging + LDS-broadcast
// scan + in-block masked sum), plus a last-block-done finalize:
//  - each block writes ONE float2 partial to its unique slot
//  - __threadfence + device atomicAdd ticket; the 256th block re-reads all
//    partials in FIXED order and writes out[b] (deterministic values).
// Counter is zeroed by a tiny hipMemsetAsync node before this kernel.
//   min_n d2 = pn - 2 * max_n (p.q - 0.5|q|^2),  q.w = -0.5|q|^2
// ---------------------------------------------------------------------------
__global__ __launch_bounds__(TPB) void chamfer_main(
    const float* __restrict__ c, const float* __restrict__ depth,
    const float* __restrict__ pc, float2* __restrict__ partial,
    int* __restrict__ counter, float* __restrict__ out,
    int res, int M, int N)
{
    __shared__ float4 spts[MAXPTS];           // 32 KB
    __shared__ float red[WAVES][RAYS_PB];     // 8 KB
    __shared__ float smax[WAVES];
    __shared__ float bs[RPT], bc[RPT];
    __shared__ int isLast;

    int tile = blockIdx.x, b = blockIdx.y;
    int tid = threadIdx.x, w = tid >> 6, lane = tid & 63;

    const float* cb = c + b * 25;
    float fx = cb[16], sk = cb[17], cx = cb[18];
    float fy = cb[20], cy = cb[21];
    float ox = cb[3], oy = cb[7], oz = cb[11];

    // ---- ray setup: 4 rays per thread ----
    float px[RPT], py[RPT], pz[RPT], pn[RPT], dep[RPT], mxs[RPT];
    #pragma unroll
    for (int r = 0; r < RPT; ++r) {
        int m = tile * RAYS_PB + lane + 64 * r;
        int mm = min(m, M - 1);
        int i = mm / res, j = mm - i * res;
        float x = (j + 0.5f) / (float)res;
        float y = (i + 0.5f) / (float)res;
        float xl = (x - cx + cy * sk / fy - sk * y / fy) / fx;
        float yl = (y - cy) / fy;
        float wx = cb[0] * xl + cb[1] * yl + cb[2] + cb[3];
        float wy = cb[4] * xl + cb[5] * yl + cb[6] + cb[7];
        float wz = cb[8] * xl + cb[9] * yl + cb[10] + cb[11];
        float dx = wx - ox, dy = wy - oy, dz = wz - oz;
        float nrm = fmaxf(sqrtf(dx * dx + dy * dy + dz * dz), 1e-12f);
        dx /= nrm; dy /= nrm; dz /= nrm;
        float d = depth[(size_t)b * M + mm];
        dep[r] = d;
        px[r] = fmaf(d, dx, ox);
        py[r] = fmaf(d, dy, oy);
        pz[r] = fmaf(d, dz, oz);
        pn[r] = px[r] * px[r] + py[r] * py[r] + pz[r] * pz[r];
        mxs[r] = -3.4e38f;
    }

    // ---- stage + scan all N points (chunked; N<=MAXPTS -> single pass) ----
    float mdl = 0.0f;   // squared distances >= 0
    for (int n0 = 0; n0 < N; n0 += MAXPTS) {
        int kc = min(N - n0, MAXPTS);
        if (n0) __syncthreads();   // previous chunk's reads complete
        const float* src = pc + ((size_t)b * N + n0) * 3;
        for (int p = tid; p < kc; p += TPB) {
            float qx = src[3 * p], qy = src[3 * p + 1], qz = src[3 * p + 2];
            float qn = qx * qx + qy * qy + qz * qz;
            spts[p] = make_float4(qx, qy, qz, -0.5f * qn);
            float dx = qx - ox, dy = qy - oy, dz = qz - oz;
            mdl = fmaxf(mdl, dx * dx + dy * dy + dz * dz);
        }
        __syncthreads();

        int cpw = (kc + WAVES - 1) / WAVES;
        int s0 = min(w * cpw, kc);
        int s1 = min(s0 + cpw, kc);
        #pragma unroll 8
        for (int k = s0; k < s1; ++k) {
            float4 q = spts[k];   // wave-uniform broadcast, conflict-free
            #pragma unroll
            for (int r = 0; r < RPT; ++r) {
                float s = fmaf(pz[r], q.z, q.w);
                s = fmaf(py[r], q.y, s);
                s = fmaf(px[r], q.x, s);
                mxs[r] = fmaxf(mxs[r], s);
            }
        }
    }

    // ---- per-wave maxdist partial + per-ray max handoff ----
    for (int off = 32; off; off >>= 1) mdl = fmaxf(mdl, __shfl_down(mdl, off));
    if (lane == 0) smax[w] = mdl;
    #pragma unroll
    for (int r = 0; r < RPT; ++r) red[w][lane + 64 * r] = mxs[r];
    __syncthreads();

    // ---- combine: thread tid (<256) owns ray tid ----
    float s = 0.f, cnt = 0.f;
    if (tid < RAYS_PB) {
        float m2 = smax[0];
        #pragma unroll
        for (int ww = 1; ww < WAVES; ++ww) m2 = fmaxf(m2, smax[ww]);
        float thr = sqrtf(m2);

        float mx = red[0][tid];
        #pragma unroll
        for (int ww = 1; ww < WAVES; ++ww) mx = fmaxf(mx, red[ww][tid]);
        // ray tid's pn/dep live in this thread's slot r == w (static select)
        float pnk = pn[0], dk = dep[0];
        #pragma unroll
        for (int r = 1; r < RPT; ++r) if (w == r) { pnk = pn[r]; dk = dep[r]; }
        int m = tile * RAYS_PB + tid;
        if (m < M) {
            float md = fmaxf(fmaf(-2.0f, mx, pnk), 0.0f);
            if (dk < thr) { s = md; cnt = 1.0f; }
        }
    }
    for (int off = 32; off; off >>= 1) {
        s += __shfl_down(s, off);
        cnt += __shfl_down(cnt, off);
    }
    if (tid < RAYS_PB && lane == 0) { bs[w] = s; bc[w] = cnt; }
    __syncthreads();

    // ---- publish partial + last-block finalize ----
    if (tid == 0) {
        float S = 0.f, C = 0.f;
        #pragma unroll
        for (int ww = 0; ww < RPT; ++ww) { S += bs[ww]; C += bc[ww]; }
        partial[(size_t)b * gridDim.x + blockIdx.x] = make_float2(S, C);
        __threadfence();                       // release partial
        int t = atomicAdd(counter, 1);         // device-scope
        isLast = (t == (int)(gridDim.x * gridDim.y) - 1) ? 1 : 0;
    }
    __syncthreads();
    if (isLast) {
        __threadfence();                       // acquire all partials
        int nt = gridDim.x, Bn = gridDim.y;
        if (w < Bn) {
            float S2 = 0.f, C2 = 0.f;
            for (int i = lane; i < nt; i += 64) {
                float2 p = partial[(size_t)w * nt + i];
                S2 += p.x; C2 += p.y;
            }
            for (int off = 32; off; off >>= 1) {
                S2 += __shfl_down(S2, off);
                C2 += __shfl_down(C2, off);
            }
            if (lane == 0) out[w] = S2 / fmaxf(C2, 1.0f);
        }
    }
}

extern "C" void kernel_launch(void* const* d_in, const int* in_sizes, int n_in,
                              void* d_out, int out_size, void* d_ws, size_t ws_size,
                              hipStream_t stream) {
    const float* c     = (const float*)d_in[0];
    const float* depth = (const float*)d_in[1];
    const float* pc    = (const float*)d_in[2];

    int B = in_sizes[0] / 25;
    int M = in_sizes[1] / B;
    int N = in_sizes[2] / (3 * B);
    int res = 1;
    while (res * res < M) ++res;

    int ntiles = (M + RAYS_PB - 1) / RAYS_PB;

    char* base = (char*)d_ws;
    float2* partial = (float2*)base;
    size_t o = (size_t)B * ntiles * sizeof(float2);
    o = (o + 255) & ~(size_t)255;
    int* counter = (int*)(base + o);

    hipMemsetAsync(counter, 0, sizeof(int), stream);
    chamfer_main<<<dim3(ntiles, B), TPB, 0, stream>>>(
        c, depth, pc, partial, counter, (float*)d_out, res, M, N);
}